// Round 4
// baseline (907.680 us; speedup 1.0000x reference)
//
#include <hip/hip_runtime.h>
#include <hip/hip_bf16.h>

#define IN_DIM 1024
#define H_DIM  1024
#define C_DIM  16
#define B_DIM  4096
#define K_DIM  2048      // IN + H
#define N_DIM  32768     // C * 2H
#define M_DIM  4096      // B
#define NSTEP  256       // 8 tiles * 32 K-steps per persistent block

typedef __attribute__((ext_vector_type(8))) short short8;
typedef __attribute__((ext_vector_type(4))) float f32x4;

__device__ __forceinline__ unsigned short f2bf_rne(float f) {
  union { float f; unsigned u; } a; a.f = f;
  unsigned r = a.u + 0x7FFFu + ((a.u >> 16) & 1u);
  return (unsigned short)(r >> 16);
}

// Pack rows: out[r][0:1024] = bf16(xs[r][:]), out[r][1024:2048] = bf16(hs[r][:])
__global__ void convert_pack_kernel(const float* __restrict__ xs,
                                    const float* __restrict__ hs,
                                    unsigned short* __restrict__ out,
                                    int rows) {
  long total = (long)rows * (K_DIM / 8);
  for (long i = blockIdx.x * (long)blockDim.x + threadIdx.x; i < total;
       i += (long)gridDim.x * blockDim.x) {
    long e = i * 8;
    int r = (int)(e >> 11);
    int k = (int)(e & 2047);
    const float* src = (k < IN_DIM) ? (xs + (long)r * IN_DIM + k)
                                    : (hs + (long)r * H_DIM + (k - IN_DIM));
    float4 v0 = *(const float4*)(src);
    float4 v1 = *(const float4*)(src + 4);
    union { unsigned short u[8]; short8 s; } p;
    p.u[0] = f2bf_rne(v0.x); p.u[1] = f2bf_rne(v0.y);
    p.u[2] = f2bf_rne(v0.z); p.u[3] = f2bf_rne(v0.w);
    p.u[4] = f2bf_rne(v1.x); p.u[5] = f2bf_rne(v1.y);
    p.u[6] = f2bf_rne(v1.z); p.u[7] = f2bf_rne(v1.w);
    *(short8*)(out + e) = p.s;
  }
}

__device__ __forceinline__ void gload_lds16(const void* g, void* l) {
  __builtin_amdgcn_global_load_lds(
      (const __attribute__((address_space(1))) unsigned int*)g,
      (__attribute__((address_space(3))) unsigned int*)l, 16, 0, 0);
}

// Fragment read: inline-asm ds_read_b128 on a raw LDS byte offset.
// Opaque to the compiler's waitcnt pass -> no conservative vmcnt(0) inserted
// for aliasing with global_load_lds DMA writes. Ordering is enforced by our
// explicit barriers + counted vmcnt + lgkmcnt(0)+sched_barrier(0) (rule #18).
__device__ __forceinline__ short8 ldsr16(unsigned addr) {
  short8 r;
  asm volatile("ds_read_b128 %0, %1" : "=v"(r) : "v"(addr));
  return r;
}

// C = A(M x K) * Bt(N x K)^T + bias, fused sigmoid/tanh epilogue.
// Persistent: grid 256 (1 block/CU). Each block: fixed nt, marches 8 m-tiles
// as one continuous 256-step pipeline. 256x256 tile, BK=64, 8 waves (2Mx4N).
// 2 double-buffers (128 KiB LDS: A0@0, A1@32KB, B0@64KB, B1@96KB bytes),
// 4 phases/step, 16 MFMA/phase, progressive quarter staging, vmcnt(6).
__global__ void __launch_bounds__(512, 2)
gemm_act_kernel(const short* __restrict__ A,   // [M][K] bf16 bits
                const short* __restrict__ Bt,  // [N][K] bf16 bits
                const float* __restrict__ bias,// [N]
                float* __restrict__ out) {
  extern __shared__ short lds[];

  // bijective XCD swizzle (nwg = 256, divisible by 8)
  int cpx = (int)gridDim.x >> 3;
  int wg  = ((int)blockIdx.x & 7) * cpx + ((int)blockIdx.x >> 3);
  const int nt    = wg >> 1;        // 0..127
  const int mgrp  = wg & 1;
  const int n0    = nt * 256;
  const int mbase = mgrp * 2048;    // tile j: m0 = mbase + j*256

  const int tid  = (int)threadIdx.x;
  const int lane = tid & 63;
  const int wid  = tid >> 6;
  const int wr   = wid >> 2;   // 0..1 -> wave rows wr*128
  const int wc   = wid & 3;    // 0..3 -> wave cols wc*64

  // ---- staging (T2: swizzled global source, linear LDS dest) ----
  const int srow = tid >> 3;                 // 0..63 row within quarter
  const int sc   = (tid & 7) ^ (srow & 7);   // swizzled src 16B chunk
  const long Arow = (long)(mbase + srow) * K_DIM + sc * 8;
  const long Brow = (long)(n0 + srow) * K_DIM + sc * 8;
  const int  dOff = srow * 64 + (tid & 7) * 8;   // LDS dest (shorts)

  // buffers (short* for DMA dest): A0=lds, A1=lds+16384, B0=+32768, B1=+49152
  auto stageA = [&](int s, int r0, int half) {
    const short* g = A + Arow + (long)(((s >> 5) << 8) + r0) * K_DIM + (s & 31) * 64;
    gload_lds16(g, lds + half * 16384 + r0 * 64 + dOff);
  };
  auto stageB = [&](int s, int r0, int half) {
    const short* g = Bt + Brow + (long)r0 * K_DIM + (s & 31) * 64;
    gload_lds16(g, lds + 32768 + half * 16384 + r0 * 64 + dOff);
  };

  // ---- fragment LDS byte offsets (swizzled read side) ----
  const int fr = lane & 15;
  const int g8 = lane >> 4;
  unsigned aoffB[8][2], boffB[4][2];
#pragma unroll
  for (int mi = 0; mi < 8; ++mi) {
    int r = wr * 128 + mi * 16 + fr;
#pragma unroll
    for (int kk = 0; kk < 2; ++kk)
      aoffB[mi][kk] = 2u * (r * 64 + (((kk * 4 + g8) ^ (r & 7)) << 3));
  }
#pragma unroll
  for (int ni = 0; ni < 4; ++ni) {
    int r = wc * 64 + ni * 16 + fr;
#pragma unroll
    for (int kk = 0; kk < 2; ++kk)
      boffB[ni][kk] = 2u * (r * 64 + (((kk * 4 + g8) ^ (r & 7)) << 3));
  }

  // ---- epilogue constants: bias hoisted (no VMEM loads inside loop) ----
  const int crow = (lane >> 4) * 4;
  const int ccol = lane & 15;
  const long HALF = (long)B_DIM * C_DIM * H_DIM;  // 67108864
  float bia[4]; int cg[4], og[4];
#pragma unroll
  for (int ni = 0; ni < 4; ++ni) {
    int gn = n0 + wc * 64 + ni * 16 + ccol;
    bia[ni] = bias[gn];
    cg[ni] = gn >> 11;
    og[ni] = gn & 2047;
  }

  f32x4 acc[8][4] = {};

  // ---- prologue: step0 full + step1 {B, A-low}; leave 6 in flight ----
  stageB(0, 0, 0); stageB(0, 64, 0); stageB(0, 128, 0); stageB(0, 192, 0);
  stageA(0, 0, 0); stageA(0, 64, 0); stageA(0, 128, 0); stageA(0, 192, 0);
  stageB(1, 0, 1); stageB(1, 64, 1); stageB(1, 128, 1); stageB(1, 192, 1);
  stageA(1, 0, 1); stageA(1, 128, 1);
  asm volatile("s_waitcnt vmcnt(6)" ::: "memory");
  __builtin_amdgcn_s_barrier();

  // One step: 4 phases. Slot freedom (race-checked, as round 3):
  //  ph0 MFMA lo x kk0 | stage A-up(s+1)->other ; ph1 lo x kk1 | B h0(s+2)->cur
  //  ph2 hi x kk0 | B h1(s+2)->cur ; ph3 hi x kk1 | A-low(s+2)->cur
  auto step = [&](int s, int cur) {
    const bool s1 = (s + 1) < NSTEP;
    const bool s2 = (s + 2) < NSTEP;
    const unsigned bA = cur ? 32768u : 0u;
    const unsigned bB = cur ? 98304u : 65536u;
    short8 av0[4], av1[4], bv0[4], bv1[4];
    // ---- ph0 ----
#pragma unroll
    for (int i = 0; i < 4; ++i) av0[i] = ldsr16(bA + aoffB[i][0]);
#pragma unroll
    for (int j = 0; j < 4; ++j) bv0[j] = ldsr16(bB + boffB[j][0]);
#pragma unroll
    for (int j = 0; j < 4; ++j) bv1[j] = ldsr16(bB + boffB[j][1]);
    if (s1) { stageA(s + 1, 64, cur ^ 1); stageA(s + 1, 192, cur ^ 1); }
    __builtin_amdgcn_s_barrier();
    asm volatile("s_waitcnt lgkmcnt(0)" ::: "memory");
    __builtin_amdgcn_sched_barrier(0);
    __builtin_amdgcn_s_setprio(1);
#pragma unroll
    for (int i = 0; i < 4; ++i)
#pragma unroll
      for (int j = 0; j < 4; ++j)
        acc[i][j] = __builtin_amdgcn_mfma_f32_16x16x32_bf16(av0[i], bv0[j], acc[i][j], 0, 0, 0);
    __builtin_amdgcn_s_setprio(0);
    __builtin_amdgcn_s_barrier();
    // ---- ph1 ----
#pragma unroll
    for (int i = 0; i < 4; ++i) av1[i] = ldsr16(bA + aoffB[i][1]);
    if (s2) { stageB(s + 2, 0, cur); stageB(s + 2, 64, cur); }
    __builtin_amdgcn_s_barrier();
    asm volatile("s_waitcnt lgkmcnt(0)" ::: "memory");
    __builtin_amdgcn_sched_barrier(0);
    __builtin_amdgcn_s_setprio(1);
#pragma unroll
    for (int i = 0; i < 4; ++i)
#pragma unroll
      for (int j = 0; j < 4; ++j)
        acc[i][j] = __builtin_amdgcn_mfma_f32_16x16x32_bf16(av1[i], bv1[j], acc[i][j], 0, 0, 0);
    __builtin_amdgcn_s_setprio(0);
    __builtin_amdgcn_s_barrier();
    // ---- ph2 ----
#pragma unroll
    for (int i = 0; i < 4; ++i) av0[i] = ldsr16(bA + aoffB[4 + i][0]);
    if (s2) { stageB(s + 2, 128, cur); stageB(s + 2, 192, cur); }
    __builtin_amdgcn_s_barrier();
    asm volatile("s_waitcnt lgkmcnt(0)" ::: "memory");
    __builtin_amdgcn_sched_barrier(0);
    __builtin_amdgcn_s_setprio(1);
#pragma unroll
    for (int i = 0; i < 4; ++i)
#pragma unroll
      for (int j = 0; j < 4; ++j)
        acc[4 + i][j] = __builtin_amdgcn_mfma_f32_16x16x32_bf16(av0[i], bv0[j], acc[4 + i][j], 0, 0, 0);
    __builtin_amdgcn_s_setprio(0);
    __builtin_amdgcn_s_barrier();
    // ---- ph3 ----
#pragma unroll
    for (int i = 0; i < 4; ++i) av1[i] = ldsr16(bA + aoffB[4 + i][1]);
    if (s2) { stageA(s + 2, 0, cur); stageA(s + 2, 128, cur); }
    __builtin_amdgcn_s_barrier();
    asm volatile("s_waitcnt lgkmcnt(0)" ::: "memory");
    __builtin_amdgcn_sched_barrier(0);
    __builtin_amdgcn_s_setprio(1);
#pragma unroll
    for (int i = 0; i < 4; ++i)
#pragma unroll
      for (int j = 0; j < 4; ++j)
        acc[4 + i][j] = __builtin_amdgcn_mfma_f32_16x16x32_bf16(av1[i], bv1[j], acc[4 + i][j], 0, 0, 0);
    __builtin_amdgcn_s_setprio(0);
    // boundary: drain step s+1 fully (oldest 8, incl. any epilogue stores)
    if (s2) asm volatile("s_waitcnt vmcnt(6)" ::: "memory");
    else    asm volatile("s_waitcnt vmcnt(0)" ::: "memory");
    __builtin_amdgcn_s_barrier();
    // ---- tile boundary: dump accumulators, reset ----
    if ((s & 31) == 31) {
      int m0t = mbase + ((s >> 5) << 8);
#pragma unroll
      for (int mi = 0; mi < 8; ++mi) {
        int gb0 = m0t + wr * 128 + mi * 16 + crow;
#pragma unroll
        for (int ni = 0; ni < 4; ++ni) {
          int c = cg[ni], o = og[ni];
#pragma unroll
          for (int j = 0; j < 4; ++j) {
            float v = acc[mi][ni][j] + bia[ni];
            long b = gb0 + j;
            if (o < H_DIM) {  // sigmoid -> output 1 (second half)
              float r = 1.0f / (1.0f + __expf(-v));
              __builtin_nontemporal_store(r, &out[HALF + (b * C_DIM + c) * H_DIM + o]);
            } else {          // tanh -> output 0 (first half)
              float av2 = fabsf(v);
              float e = __expf(-2.0f * av2);
              float r = (1.0f - e) / (1.0f + e);
              r = (v < 0.0f) ? -r : r;
              __builtin_nontemporal_store(r, &out[(b * C_DIM + c) * H_DIM + (o - H_DIM)]);
            }
          }
          acc[mi][ni] = (f32x4){0.0f, 0.0f, 0.0f, 0.0f};
        }
      }
    }
  };

  for (int s = 0; s < NSTEP; s += 2) {
    step(s,     0);
    step(s + 1, 1);
  }
}

// Correctness-only fallback if workspace is too small for bf16 staging.
__global__ void fallback_kernel(const float* __restrict__ x,
                                const float* __restrict__ h,
                                const float* __restrict__ Wx,
                                const float* __restrict__ bx,
                                const float* __restrict__ Wh,
                                float* __restrict__ out) {
  int b = blockIdx.x;
  int c = blockIdx.y;
  __shared__ float lx[IN_DIM], lh[H_DIM];
  for (int i = threadIdx.x; i < IN_DIM; i += blockDim.x) {
    lx[i] = x[(long)b * IN_DIM + i];
    lh[i] = h[(long)b * H_DIM + i];
  }
  __syncthreads();
  const long HALF = (long)B_DIM * C_DIM * H_DIM;
  for (int o = threadIdx.x; o < 2 * H_DIM; o += blockDim.x) {
    const float* wx = Wx + ((long)c * 2 * H_DIM + o) * IN_DIM;
    const float* wh = Wh + ((long)c * 2 * H_DIM + o) * H_DIM;
    float acc = bx[c * 2 * H_DIM + o];
    for (int k = 0; k < IN_DIM; ++k) acc += lx[k] * wx[k];
    for (int k = 0; k < H_DIM; ++k) acc += lh[k] * wh[k];
    if (o < H_DIM) {
      out[HALF + ((long)b * C_DIM + c) * H_DIM + o] = 1.0f / (1.0f + __expf(-acc));
    } else {
      float av = fabsf(acc);
      float t = __expf(-2.0f * av);
      float r = (1.0f - t) / (1.0f + t);
      out[((long)b * C_DIM + c) * H_DIM + (o - H_DIM)] = (acc < 0.0f) ? -r : r;
    }
  }
}

extern "C" void kernel_launch(void* const* d_in, const int* in_sizes, int n_in,
                              void* d_out, int out_size, void* d_ws, size_t ws_size,
                              hipStream_t stream) {
  const float* x  = (const float*)d_in[0];   // (B, IN)
  const float* h  = (const float*)d_in[1];   // (B, H)
  const float* Wx = (const float*)d_in[2];   // (C, 2H, IN)
  const float* bx = (const float*)d_in[3];   // (C, 2H)
  const float* Wh = (const float*)d_in[4];   // (C, 2H, H)
  float* out = (float*)d_out;                // [cell_input | input_gate], each (B,C,H)

  const size_t needA = (size_t)M_DIM * K_DIM * sizeof(short);  // 16 MiB
  const size_t needB = (size_t)N_DIM * K_DIM * sizeof(short);  // 128 MiB
  if (ws_size < needA + needB) {
    dim3 g(B_DIM, C_DIM);
    fallback_kernel<<<g, 256, 0, stream>>>(x, h, Wx, bx, Wh, out);
    return;
  }

  unsigned short* Abf = (unsigned short*)d_ws;
  unsigned short* Bbf = (unsigned short*)((char*)d_ws + needA);

  convert_pack_kernel<<<2048, 256, 0, stream>>>(x, h, Abf, M_DIM);
  convert_pack_kernel<<<4096, 256, 0, stream>>>(Wx, Wh, Bbf, N_DIM);

  (void)hipFuncSetAttribute((const void*)gemm_act_kernel,
                            hipFuncAttributeMaxDynamicSharedMemorySize, 131072);
  gemm_act_kernel<<<256, 512, 131072, stream>>>((const short*)Abf, (const short*)Bbf,
                                                bx, out);
}

// Round 5
// 735.061 us; speedup vs baseline: 1.2348x; 1.2348x over previous
//
#include <hip/hip_runtime.h>
#include <hip/hip_bf16.h>

#define IN_DIM 1024
#define H_DIM  1024
#define C_DIM  16
#define B_DIM  4096
#define K_DIM  2048      // IN + H
#define N_DIM  32768     // C * 2H
#define M_DIM  4096      // B
#define NT     32        // K_DIM / 64 K-steps

typedef __attribute__((ext_vector_type(8))) short short8;
typedef __attribute__((ext_vector_type(4))) float f32x4;

__device__ __forceinline__ unsigned short f2bf_rne(float f) {
  union { float f; unsigned u; } a; a.f = f;
  unsigned r = a.u + 0x7FFFu + ((a.u >> 16) & 1u);
  return (unsigned short)(r >> 16);
}

// Pack rows: out[r][0:1024] = bf16(xs[r][:]), out[r][1024:2048] = bf16(hs[r][:])
__global__ void convert_pack_kernel(const float* __restrict__ xs,
                                    const float* __restrict__ hs,
                                    unsigned short* __restrict__ out,
                                    int rows) {
  long total = (long)rows * (K_DIM / 8);
  for (long i = blockIdx.x * (long)blockDim.x + threadIdx.x; i < total;
       i += (long)gridDim.x * blockDim.x) {
    long e = i * 8;
    int r = (int)(e >> 11);
    int k = (int)(e & 2047);
    const float* src = (k < IN_DIM) ? (xs + (long)r * IN_DIM + k)
                                    : (hs + (long)r * H_DIM + (k - IN_DIM));
    float4 v0 = *(const float4*)(src);
    float4 v1 = *(const float4*)(src + 4);
    union { unsigned short u[8]; short8 s; } p;
    p.u[0] = f2bf_rne(v0.x); p.u[1] = f2bf_rne(v0.y);
    p.u[2] = f2bf_rne(v0.z); p.u[3] = f2bf_rne(v0.w);
    p.u[4] = f2bf_rne(v1.x); p.u[5] = f2bf_rne(v1.y);
    p.u[6] = f2bf_rne(v1.z); p.u[7] = f2bf_rne(v1.w);
    *(short8*)(out + e) = p.s;
  }
}

// Opaque LDS-DMA: compiler's waitcnt pass cannot see an LDS write here, so it
// inserts no conservative vmcnt(0) before our IR ds_reads; ordering is ours
// (counted vmcnt + barriers). "memory" clobber pins IR loads/stores around it.
// HW writes lane i at m0 + i*16; our dest layout is exactly lane-linear.
__device__ __forceinline__ void dma16(const short* g, int ldsOff) {
  asm volatile("s_mov_b32 m0, %1\n\t"
               "global_load_lds_dwordx4 %0, off"
               :: "v"(g), "s"(ldsOff) : "memory");
}

// C = A(M x K) * Bt(N x K)^T + bias, fused sigmoid/tanh epilogue.
// 256x256 tile, BK=64, 8 waves (2Mx4N), wave tile 128x64, 2 double-buffers.
// 4 phases/step, 16 MFMA/phase, reads spread 8/8/4/4, SINGLE barrier per
// phase (post-MFMA) -> lagging-wave reads overlap other waves' MFMA.
// Counted vmcnt(6) once per step; opaque DMA so it's the only VMEM wait.
__global__ void __launch_bounds__(512, 2)
gemm_act_kernel(const short* __restrict__ A,   // [M][K] bf16 bits
                const short* __restrict__ Bt,  // [N][K] bf16 bits
                const float* __restrict__ bias,// [N]
                float* __restrict__ out) {
  extern __shared__ short lds[];
  // byte layout: A0@0, A1@32768, B0@65536, B1@98304 (short idx: /2)

  // bijective XCD swizzle (nwg = 2048, divisible by 8); m-fastest tiling
  int cpx = (int)gridDim.x >> 3;
  int wg  = ((int)blockIdx.x & 7) * cpx + ((int)blockIdx.x >> 3);
  int mt = wg & 15;           // M/256 = 16 tiles
  int nt = wg >> 4;           // N/256 = 128 tiles
  int m0 = mt * 256;
  int n0 = nt * 256;

  const int tid  = (int)threadIdx.x;
  const int lane = tid & 63;
  const int wid  = tid >> 6;
  const int wr   = wid >> 2;   // wave rows wr*128
  const int wc   = wid & 3;    // wave cols wc*64

  // ---- epilogue constants FIRST: only IR vmem loads, before any DMA ----
  const int crow = (lane >> 4) * 4;
  const int ccol = lane & 15;
  const long HALF = (long)B_DIM * C_DIM * H_DIM;  // 67108864
  float bia[4]; int cg[4], og[4];
#pragma unroll
  for (int ni = 0; ni < 4; ++ni) {
    int gn = n0 + wc * 64 + ni * 16 + ccol;
    bia[ni] = bias[gn];
    cg[ni] = gn >> 11;
    og[ni] = gn & 2047;
  }

  // ---- staging (T2: swizzled global source, lane-linear LDS dest) ----
  const int srow = tid >> 3;                 // 0..63 row within quarter
  const int sc   = (tid & 7) ^ (srow & 7);   // swizzled src 16B chunk
  const short* Abase = A  + (long)(m0 + srow) * K_DIM + sc * 8;
  const short* Bbase = Bt + (long)(n0 + srow) * K_DIM + sc * 8;
  const int wb = __builtin_amdgcn_readfirstlane((tid >> 6) * 1024); // wave LDS base

  auto stA = [&](int kt, int r0, int buf) {
    dma16(Abase + (long)r0 * K_DIM + kt * 64, buf * 32768 + r0 * 128 + wb);
  };
  auto stB = [&](int kt, int r0, int buf) {
    dma16(Bbase + (long)r0 * K_DIM + kt * 64, 65536 + buf * 32768 + r0 * 128 + wb);
  };

  // ---- fragment LDS offsets in shorts (swizzled read side) ----
  const int fr = lane & 15;
  const int g8 = lane >> 4;
  int aoffS[8][2], boffS[4][2];
#pragma unroll
  for (int mi = 0; mi < 8; ++mi) {
    int r = wr * 128 + mi * 16 + fr;
#pragma unroll
    for (int kk = 0; kk < 2; ++kk)
      aoffS[mi][kk] = r * 64 + (((kk * 4 + g8) ^ (r & 7)) << 3);
  }
#pragma unroll
  for (int ni = 0; ni < 4; ++ni) {
    int r = wc * 64 + ni * 16 + fr;
#pragma unroll
    for (int kk = 0; kk < 2; ++kk)
      boffS[ni][kk] = r * 64 + (((kk * 4 + g8) ^ (r & 7)) << 3);
  }

  f32x4 acc[8][4] = {};

  // ---- prologue: tile0 full (8 oldest), then B(1)x4 + A-low(1)x2 ----
  stA(0, 0, 0); stA(0, 64, 0); stA(0, 128, 0); stA(0, 192, 0);
  stB(0, 0, 0); stB(0, 64, 0); stB(0, 128, 0); stB(0, 192, 0);
  stB(1, 0, 1); stB(1, 64, 1); stB(1, 128, 1); stB(1, 192, 1);
  stA(1, 0, 1); stA(1, 128, 1);
  asm volatile("s_waitcnt vmcnt(6)" ::: "memory");
  __builtin_amdgcn_s_barrier();

  // Per step (race-checked): ph0 reads {A-lo k0, B k0}, stages A-up64(t+1);
  // ph1 reads {A-lo k1, B k1}, stages A-up192(t+1); ph2 reads {A-hi k0},
  // stages {B h0(t+2), A-lo0(t+2)}; ph3 reads {A-hi k1}, stages
  // {B h1(t+2), A-lo128(t+2)}; boundary vmcnt(6) retires exactly tile t+1.
  auto iter = [&](int t, int cur) {
    const bool s1 = (t + 1) < NT;
    const bool s2 = (t + 2) < NT;
    const short* cA = lds + cur * 16384;
    const short* cB = lds + 32768 + cur * 16384;
    const int nx = cur ^ 1;
    short8 av[4], bv0[4], bv1[4];
    // ---- ph0 ----
#pragma unroll
    for (int i = 0; i < 4; ++i) av[i]  = *(const short8*)(cA + aoffS[i][0]);
#pragma unroll
    for (int j = 0; j < 4; ++j) bv0[j] = *(const short8*)(cB + boffS[j][0]);
    if (s1) stA(t + 1, 64, nx);
    __builtin_amdgcn_s_setprio(1);
#pragma unroll
    for (int i = 0; i < 4; ++i)
#pragma unroll
      for (int j = 0; j < 4; ++j)
        acc[i][j] = __builtin_amdgcn_mfma_f32_16x16x32_bf16(av[i], bv0[j], acc[i][j], 0, 0, 0);
    __builtin_amdgcn_s_setprio(0);
    __builtin_amdgcn_s_barrier();
    // ---- ph1 ----
#pragma unroll
    for (int i = 0; i < 4; ++i) av[i]  = *(const short8*)(cA + aoffS[i][1]);
#pragma unroll
    for (int j = 0; j < 4; ++j) bv1[j] = *(const short8*)(cB + boffS[j][1]);
    if (s1) stA(t + 1, 192, nx);
    __builtin_amdgcn_s_setprio(1);
#pragma unroll
    for (int i = 0; i < 4; ++i)
#pragma unroll
      for (int j = 0; j < 4; ++j)
        acc[i][j] = __builtin_amdgcn_mfma_f32_16x16x32_bf16(av[i], bv1[j], acc[i][j], 0, 0, 0);
    __builtin_amdgcn_s_setprio(0);
    __builtin_amdgcn_s_barrier();
    // ---- ph2 ----
#pragma unroll
    for (int i = 0; i < 4; ++i) av[i] = *(const short8*)(cA + aoffS[4 + i][0]);
    if (s2) { stB(t + 2, 0, cur); stB(t + 2, 64, cur); stA(t + 2, 0, cur); }
    __builtin_amdgcn_s_setprio(1);
#pragma unroll
    for (int i = 0; i < 4; ++i)
#pragma unroll
      for (int j = 0; j < 4; ++j)
        acc[4 + i][j] = __builtin_amdgcn_mfma_f32_16x16x32_bf16(av[i], bv0[j], acc[4 + i][j], 0, 0, 0);
    __builtin_amdgcn_s_setprio(0);
    __builtin_amdgcn_s_barrier();
    // ---- ph3 ----
#pragma unroll
    for (int i = 0; i < 4; ++i) av[i] = *(const short8*)(cA + aoffS[4 + i][1]);
    if (s2) { stB(t + 2, 128, cur); stB(t + 2, 192, cur); stA(t + 2, 128, cur); }
    __builtin_amdgcn_s_setprio(1);
#pragma unroll
    for (int i = 0; i < 4; ++i)
#pragma unroll
      for (int j = 0; j < 4; ++j)
        acc[4 + i][j] = __builtin_amdgcn_mfma_f32_16x16x32_bf16(av[i], bv1[j], acc[4 + i][j], 0, 0, 0);
    __builtin_amdgcn_s_setprio(0);
    if (s2)      asm volatile("s_waitcnt vmcnt(6)" ::: "memory");
    else if (s1) asm volatile("s_waitcnt vmcnt(0)" ::: "memory");
    __builtin_amdgcn_s_barrier();
  };

  for (int t = 0; t < NT; t += 2) {
    iter(t,     0);
    iter(t + 1, 1);
  }

  // ---- epilogue: C/D layout col=lane&15, row=(lane>>4)*4+j ----
#pragma unroll
  for (int mi = 0; mi < 8; ++mi) {
    int gb0 = m0 + wr * 128 + mi * 16 + crow;
#pragma unroll
    for (int ni = 0; ni < 4; ++ni) {
      int c = cg[ni], o = og[ni];
#pragma unroll
      for (int j = 0; j < 4; ++j) {
        float v = acc[mi][ni][j] + bia[ni];
        long b = gb0 + j;
        if (o < H_DIM) {  // input_gate = sigmoid -> output 1 (second half)
          float r = 1.0f / (1.0f + __expf(-v));
          __builtin_nontemporal_store(r, &out[HALF + (b * C_DIM + c) * H_DIM + o]);
        } else {          // cell_input = tanh -> output 0 (first half)
          float av2 = fabsf(v);
          float e = __expf(-2.0f * av2);
          float r = (1.0f - e) / (1.0f + e);
          r = (v < 0.0f) ? -r : r;
          __builtin_nontemporal_store(r, &out[(b * C_DIM + c) * H_DIM + (o - H_DIM)]);
        }
      }
    }
  }
}

// Correctness-only fallback if workspace is too small for bf16 staging.
__global__ void fallback_kernel(const float* __restrict__ x,
                                const float* __restrict__ h,
                                const float* __restrict__ Wx,
                                const float* __restrict__ bx,
                                const float* __restrict__ Wh,
                                float* __restrict__ out) {
  int b = blockIdx.x;
  int c = blockIdx.y;
  __shared__ float lx[IN_DIM], lh[H_DIM];
  for (int i = threadIdx.x; i < IN_DIM; i += blockDim.x) {
    lx[i] = x[(long)b * IN_DIM + i];
    lh[i] = h[(long)b * H_DIM + i];
  }
  __syncthreads();
  const long HALF = (long)B_DIM * C_DIM * H_DIM;
  for (int o = threadIdx.x; o < 2 * H_DIM; o += blockDim.x) {
    const float* wx = Wx + ((long)c * 2 * H_DIM + o) * IN_DIM;
    const float* wh = Wh + ((long)c * 2 * H_DIM + o) * H_DIM;
    float acc = bx[c * 2 * H_DIM + o];
    for (int k = 0; k < IN_DIM; ++k) acc += lx[k] * wx[k];
    for (int k = 0; k < H_DIM; ++k) acc += lh[k] * wh[k];
    if (o < H_DIM) {
      out[HALF + ((long)b * C_DIM + c) * H_DIM + o] = 1.0f / (1.0f + __expf(-acc));
    } else {
      float av = fabsf(acc);
      float t = __expf(-2.0f * av);
      float r = (1.0f - t) / (1.0f + t);
      out[((long)b * C_DIM + c) * H_DIM + (o - H_DIM)] = (acc < 0.0f) ? -r : r;
    }
  }
}

extern "C" void kernel_launch(void* const* d_in, const int* in_sizes, int n_in,
                              void* d_out, int out_size, void* d_ws, size_t ws_size,
                              hipStream_t stream) {
  const float* x  = (const float*)d_in[0];   // (B, IN)
  const float* h  = (const float*)d_in[1];   // (B, H)
  const float* Wx = (const float*)d_in[2];   // (C, 2H, IN)
  const float* bx = (const float*)d_in[3];   // (C, 2H)
  const float* Wh = (const float*)d_in[4];   // (C, 2H, H)
  float* out = (float*)d_out;                // [cell_input | input_gate], each (B,C,H)

  const size_t needA = (size_t)M_DIM * K_DIM * sizeof(short);  // 16 MiB
  const size_t needB = (size_t)N_DIM * K_DIM * sizeof(short);  // 128 MiB
  if (ws_size < needA + needB) {
    dim3 g(B_DIM, C_DIM);
    fallback_kernel<<<g, 256, 0, stream>>>(x, h, Wx, bx, Wh, out);
    return;
  }

  unsigned short* Abf = (unsigned short*)d_ws;
  unsigned short* Bbf = (unsigned short*)((char*)d_ws + needA);

  convert_pack_kernel<<<2048, 256, 0, stream>>>(x, h, Abf, M_DIM);
  convert_pack_kernel<<<4096, 256, 0, stream>>>(Wx, Wh, Bbf, N_DIM);

  (void)hipFuncSetAttribute((const void*)gemm_act_kernel,
                            hipFuncAttributeMaxDynamicSharedMemorySize, 131072);
  gemm_act_kernel<<<2048, 512, 131072, stream>>>((const short*)Abf, (const short*)Bbf,
                                                 bx, out);
}

// Round 7
// 709.905 us; speedup vs baseline: 1.2786x; 1.0354x over previous
//
#include <hip/hip_runtime.h>
#include <hip/hip_bf16.h>

#define IN_DIM 1024
#define H_DIM  1024
#define C_DIM  16
#define B_DIM  4096
#define K_DIM  2048      // IN + H
#define N_DIM  32768     // C * 2H
#define M_DIM  4096      // B
#define NT     32        // K_DIM / 64 K-steps

typedef __attribute__((ext_vector_type(8))) short short8;
typedef __attribute__((ext_vector_type(4))) float f32x4;

__device__ __forceinline__ unsigned short f2bf_rne(float f) {
  union { float f; unsigned u; } a; a.f = f;
  unsigned r = a.u + 0x7FFFu + ((a.u >> 16) & 1u);
  return (unsigned short)(r >> 16);
}

// Pack rows: out[r][0:1024] = bf16(xs[r][:]), out[r][1024:2048] = bf16(hs[r][:])
__global__ void convert_pack_kernel(const float* __restrict__ xs,
                                    const float* __restrict__ hs,
                                    unsigned short* __restrict__ out,
                                    int rows) {
  long total = (long)rows * (K_DIM / 8);
  for (long i = blockIdx.x * (long)blockDim.x + threadIdx.x; i < total;
       i += (long)gridDim.x * blockDim.x) {
    long e = i * 8;
    int r = (int)(e >> 11);
    int k = (int)(e & 2047);
    const float* src = (k < IN_DIM) ? (xs + (long)r * IN_DIM + k)
                                    : (hs + (long)r * H_DIM + (k - IN_DIM));
    float4 v0 = *(const float4*)(src);
    float4 v1 = *(const float4*)(src + 4);
    union { unsigned short u[8]; short8 s; } p;
    p.u[0] = f2bf_rne(v0.x); p.u[1] = f2bf_rne(v0.y);
    p.u[2] = f2bf_rne(v0.z); p.u[3] = f2bf_rne(v0.w);
    p.u[4] = f2bf_rne(v1.x); p.u[5] = f2bf_rne(v1.y);
    p.u[6] = f2bf_rne(v1.z); p.u[7] = f2bf_rne(v1.w);
    *(short8*)(out + e) = p.s;
  }
}

// Opaque LDS-DMA (as round 5): compiler's waitcnt pass sees no LDS write, so
// no conservative vmcnt(0) is inserted before IR ds_reads; our counted vmcnt
// is the only VMEM wait. HW writes lane i at m0 + i*16 (lane-linear dest).
__device__ __forceinline__ void dma16(const short* g, int ldsOff) {
  asm volatile("s_mov_b32 m0, %1\n\t"
               "global_load_lds_dwordx4 %0, off"
               :: "v"(g), "s"(ldsOff) : "memory");
}

// C = A(M x K) * Bt(N x K)^T + bias, fused sigmoid/tanh epilogue.
// 256x256 tile, BK=64, 8 waves (2Mx4N), wave tile 128x64, 2 double-buffers.
// 4 phases/step, 16 MFMA/phase; ds_reads issued ONE PHASE AHEAD of their
// MFMA cluster (reg double-buffer avA/avB; bv0/bv1 alternate by k-half).
// FIX vs round 6: vmcnt waits are PER-WAVE, and staged quarters are written
// cooperatively by all 8 waves -> a reader is only safe after
//   vmcnt(N)  ->  s_barrier  ->  read.
// Waits therefore sit BEFORE the phase barrier:
//   end-ph0 vmcnt(7): retires Ahi64(t)+Ahi192(t)  [ph1+ph2 read BOTH hi
//                     quarters: wr=0 waves rows 64-127, wr=1 rows 192-255]
//   end-ph2 vmcnt(5): retires B(t+1)x4 + Alo(t+1)x2 [ph3 reads]
//   ph1/ph3: no wait. Steady-state FIFO at iter entry = 8.
__global__ void __launch_bounds__(512, 2)
gemm_act_kernel(const short* __restrict__ A,   // [M][K] bf16 bits
                const short* __restrict__ Bt,  // [N][K] bf16 bits
                const float* __restrict__ bias,// [N]
                float* __restrict__ out) {
  extern __shared__ short lds[];
  // byte layout: A0@0, A1@32768, B0@65536, B1@98304

  // bijective XCD swizzle (nwg = 2048, divisible by 8); m-fastest tiling
  int cpx = (int)gridDim.x >> 3;
  int wg  = ((int)blockIdx.x & 7) * cpx + ((int)blockIdx.x >> 3);
  int mt = wg & 15;           // M/256 = 16 tiles
  int nt = wg >> 4;           // N/256 = 128 tiles
  int m0 = mt * 256;
  int n0 = nt * 256;

  const int tid  = (int)threadIdx.x;
  const int lane = tid & 63;
  const int wid  = tid >> 6;
  const int wr   = wid >> 2;   // wave rows wr*128
  const int wc   = wid & 3;    // wave cols wc*64

  // ---- epilogue constants FIRST (only IR vmem loads, before any DMA) ----
  const int crow = (lane >> 4) * 4;
  const int ccol = lane & 15;
  const long HALF = (long)B_DIM * C_DIM * H_DIM;  // 67108864
  float bia[4]; int cg[4], og[4];
#pragma unroll
  for (int ni = 0; ni < 4; ++ni) {
    int gn = n0 + wc * 64 + ni * 16 + ccol;
    bia[ni] = bias[gn];
    cg[ni] = gn >> 11;
    og[ni] = gn & 2047;
  }

  // ---- staging (T2: swizzled global source, lane-linear LDS dest) ----
  const int srow = tid >> 3;                 // 0..63 row within quarter
  const int sc   = (tid & 7) ^ (srow & 7);   // swizzled src 16B chunk
  const short* Abase = A  + (long)(m0 + srow) * K_DIM + sc * 8;
  const short* Bbase = Bt + (long)(n0 + srow) * K_DIM + sc * 8;
  const int wb = __builtin_amdgcn_readfirstlane((tid >> 6) * 1024); // wave LDS base

  auto stA = [&](int kt, int r0, int buf) {
    dma16(Abase + (long)r0 * K_DIM + kt * 64, buf * 32768 + r0 * 128 + wb);
  };
  auto stB = [&](int kt, int r0, int buf) {
    dma16(Bbase + (long)r0 * K_DIM + kt * 64, 65536 + buf * 32768 + r0 * 128 + wb);
  };

  // ---- fragment LDS base offsets (shorts); mi/ni add mi*1024 (immediates) --
  const int fr = lane & 15;
  const int g8 = lane >> 4;
  int aoff0[2], boff0[2];
#pragma unroll
  for (int kk = 0; kk < 2; ++kk) {
    aoff0[kk] = (wr * 128 + fr) * 64 + (((kk * 4 + g8) ^ (fr & 7)) << 3);
    boff0[kk] = (wc * 64  + fr) * 64 + (((kk * 4 + g8) ^ (fr & 7)) << 3);
  }
  auto lda = [&](int buf, int mi, int kk) {
    return *(const short8*)(lds + buf * 16384 + aoff0[kk] + mi * 1024);
  };
  auto ldb = [&](int buf, int ni, int kk) {
    return *(const short8*)(lds + 32768 + buf * 16384 + boff0[kk] + ni * 1024);
  };

  f32x4 acc[8][4] = {};
  short8 avA[4], avB[4], bv0[4], bv1[4];

  auto mfma4 = [&](short8 (&a)[4], short8 (&b)[4], int mb) {
#pragma unroll
    for (int i = 0; i < 4; ++i)
#pragma unroll
      for (int j = 0; j < 4; ++j)
        acc[mb + i][j] = __builtin_amdgcn_mfma_f32_16x16x32_bf16(a[i], b[j], acc[mb + i][j], 0, 0, 0);
  };

  // ---- prologue: tile0 full (8 oldest) + B(1)x4 + A(1).lo x2 in flight ----
  stA(0, 0, 0); stA(0, 64, 0); stA(0, 128, 0); stA(0, 192, 0);
  stB(0, 0, 0); stB(0, 64, 0); stB(0, 128, 0); stB(0, 192, 0);
  stB(1, 0, 1); stB(1, 64, 1); stB(1, 128, 1); stB(1, 192, 1);
  stA(1, 0, 1); stA(1, 128, 1);
  asm volatile("s_waitcnt vmcnt(6)" ::: "memory");   // retires tile0 (all waves after barrier)
  __builtin_amdgcn_s_barrier();
  // pre-issue ph0(0)'s operands (tile0, buf0)
#pragma unroll
  for (int i = 0; i < 4; ++i) avA[i] = lda(0, i, 0);
#pragma unroll
  for (int j = 0; j < 4; ++j) bv0[j] = ldb(0, j, 0);

  // Steady-state FIFO at iter(t) entry (8): {Ahi64(t), Ahi192(t),
  //  Bq0(t+1), Bq64(t+1), Alo0(t+1), Bq128(t+1), Bq192(t+1), Alo128(t+1)}.
  // end-ph0 vmcnt(7): 9->7 retires Ahi64(t)+Ahi192(t)   (ph1/ph2 reads)
  // end-ph2 vmcnt(5): 11->5 retires B(t+1)x4+Alo(t+1)x2 (ph3 reads)
  auto iter = [&](int t, int cur, int nx) {
    const int t1 = (t + 1 < NT) ? t + 1 : NT - 1;  // clamp: FIFO-uniform tail
    const int t2 = (t + 2 < NT) ? t + 2 : NT - 1;  // (writes post-read/dead)
    // ---- ph0: MFMA(lo,k0); reads lo.k1 + B.k1; stage Ahi64(t1)->nx ----
#pragma unroll
    for (int i = 0; i < 4; ++i) avB[i] = lda(cur, i, 1);
#pragma unroll
    for (int j = 0; j < 4; ++j) bv1[j] = ldb(cur, j, 1);
    stA(t1, 64, nx);
    __builtin_amdgcn_s_setprio(1);
    mfma4(avA, bv0, 0);
    __builtin_amdgcn_s_setprio(0);
    asm volatile("s_waitcnt vmcnt(7)" ::: "memory");
    __builtin_amdgcn_s_barrier();
    // ---- ph1: MFMA(lo,k1); reads hi.k0; stage Ahi192(t1)->nx ----
#pragma unroll
    for (int i = 0; i < 4; ++i) avA[i] = lda(cur, 4 + i, 0);
    stA(t1, 192, nx);
    __builtin_amdgcn_s_setprio(1);
    mfma4(avB, bv1, 0);
    __builtin_amdgcn_s_setprio(0);
    __builtin_amdgcn_s_barrier();
    // ---- ph2: MFMA(hi,k0); reads hi.k1; stage B(t2)h0 + Alo(t2)q0 ----
#pragma unroll
    for (int i = 0; i < 4; ++i) avB[i] = lda(cur, 4 + i, 1);
    stB(t2, 0, cur); stB(t2, 64, cur); stA(t2, 0, cur);
    __builtin_amdgcn_s_setprio(1);
    mfma4(avA, bv0, 4);
    __builtin_amdgcn_s_setprio(0);
    asm volatile("s_waitcnt vmcnt(5)" ::: "memory");
    __builtin_amdgcn_s_barrier();
    // ---- ph3: MFMA(hi,k1); reads NEXT tile lo.k0 + B.k0 (from nx);
    //          stage B(t2)h1 + Alo(t2)q128 ----
#pragma unroll
    for (int i = 0; i < 4; ++i) avA[i] = lda(nx, i, 0);
#pragma unroll
    for (int j = 0; j < 4; ++j) bv0[j] = ldb(nx, j, 0);
    stB(t2, 128, cur); stB(t2, 192, cur); stA(t2, 128, cur);
    __builtin_amdgcn_s_setprio(1);
    mfma4(avB, bv1, 4);
    __builtin_amdgcn_s_setprio(0);
    __builtin_amdgcn_s_barrier();
  };

  for (int t = 0; t < NT; t += 2) {
    iter(t,     0, 1);
    iter(t + 1, 1, 0);
  }
  asm volatile("s_waitcnt vmcnt(0)" ::: "memory");

  // ---- epilogue: C/D layout col=lane&15, row=(lane>>4)*4+j ----
#pragma unroll
  for (int mi = 0; mi < 8; ++mi) {
    int gb0 = m0 + wr * 128 + mi * 16 + crow;
#pragma unroll
    for (int ni = 0; ni < 4; ++ni) {
      int c = cg[ni], o = og[ni];
#pragma unroll
      for (int j = 0; j < 4; ++j) {
        float v = acc[mi][ni][j] + bia[ni];
        long b = gb0 + j;
        if (o < H_DIM) {  // input_gate = sigmoid -> output 1 (second half)
          float r = 1.0f / (1.0f + __expf(-v));
          __builtin_nontemporal_store(r, &out[HALF + (b * C_DIM + c) * H_DIM + o]);
        } else {          // cell_input = tanh -> output 0 (first half)
          float av2 = fabsf(v);
          float e = __expf(-2.0f * av2);
          float r = (1.0f - e) / (1.0f + e);
          r = (v < 0.0f) ? -r : r;
          __builtin_nontemporal_store(r, &out[(b * C_DIM + c) * H_DIM + (o - H_DIM)]);
        }
      }
    }
  }
}

// Correctness-only fallback if workspace is too small for bf16 staging.
__global__ void fallback_kernel(const float* __restrict__ x,
                                const float* __restrict__ h,
                                const float* __restrict__ Wx,
                                const float* __restrict__ bx,
                                const float* __restrict__ Wh,
                                float* __restrict__ out) {
  int b = blockIdx.x;
  int c = blockIdx.y;
  __shared__ float lx[IN_DIM], lh[H_DIM];
  for (int i = threadIdx.x; i < IN_DIM; i += blockDim.x) {
    lx[i] = x[(long)b * IN_DIM + i];
    lh[i] = h[(long)b * H_DIM + i];
  }
  __syncthreads();
  const long HALF = (long)B_DIM * C_DIM * H_DIM;
  for (int o = threadIdx.x; o < 2 * H_DIM; o += blockDim.x) {
    const float* wx = Wx + ((long)c * 2 * H_DIM + o) * IN_DIM;
    const float* wh = Wh + ((long)c * 2 * H_DIM + o) * H_DIM;
    float acc = bx[c * 2 * H_DIM + o];
    for (int k = 0; k < IN_DIM; ++k) acc += lx[k] * wx[k];
    for (int k = 0; k < H_DIM; ++k) acc += lh[k] * wh[k];
    if (o < H_DIM) {
      out[HALF + ((long)b * C_DIM + c) * H_DIM + o] = 1.0f / (1.0f + __expf(-acc));
    } else {
      float av = fabsf(acc);
      float t = __expf(-2.0f * av);
      float r = (1.0f - t) / (1.0f + t);
      out[((long)b * C_DIM + c) * H_DIM + (o - H_DIM)] = (acc < 0.0f) ? -r : r;
    }
  }
}

extern "C" void kernel_launch(void* const* d_in, const int* in_sizes, int n_in,
                              void* d_out, int out_size, void* d_ws, size_t ws_size,
                              hipStream_t stream) {
  const float* x  = (const float*)d_in[0];   // (B, IN)
  const float* h  = (const float*)d_in[1];   // (B, H)
  const float* Wx = (const float*)d_in[2];   // (C, 2H, IN)
  const float* bx = (const float*)d_in[3];   // (C, 2H)
  const float* Wh = (const float*)d_in[4];   // (C, 2H, H)
  float* out = (float*)d_out;                // [cell_input | input_gate], each (B,C,H)

  const size_t needA = (size_t)M_DIM * K_DIM * sizeof(short);  // 16 MiB
  const size_t needB = (size_t)N_DIM * K_DIM * sizeof(short);  // 128 MiB
  if (ws_size < needA + needB) {
    dim3 g(B_DIM, C_DIM);
    fallback_kernel<<<g, 256, 0, stream>>>(x, h, Wx, bx, Wh, out);
    return;
  }

  unsigned short* Abf = (unsigned short*)d_ws;
  unsigned short* Bbf = (unsigned short*)((char*)d_ws + needA);

  convert_pack_kernel<<<2048, 256, 0, stream>>>(x, h, Abf, M_DIM);
  convert_pack_kernel<<<4096, 256, 0, stream>>>(Wx, Wh, Bbf, N_DIM);

  (void)hipFuncSetAttribute((const void*)gemm_act_kernel,
                            hipFuncAttributeMaxDynamicSharedMemorySize, 131072);
  gemm_act_kernel<<<2048, 512, 131072, stream>>>((const short*)Abf, (const short*)Bbf,
                                                 bx, out);
}